// Round 11
// baseline (144.308 us; speedup 1.0000x reference)
//
#include <hip/hip_runtime.h>

// Problem constants
#define B_  2
#define S_  1024
#define FIN 768
#define E_  768
#define H_  12
#define DH  64   // = FH = 64

typedef unsigned int uint;
typedef unsigned short ushort;
typedef __attribute__((ext_vector_type(8))) short short8;    // 8 bf16 (4 VGPRs)
typedef __attribute__((ext_vector_type(4))) float floatx4;   // MFMA acc

__device__ __forceinline__ ushort f2bf(float f) {   // RNE float->bf16 bits
    uint u = __float_as_uint(f);
    return (ushort)((u + 0x7fffu + ((u >> 16) & 1u)) >> 16);
}

__device__ __forceinline__ uint4 pack8(const ushort* p) {
    uint4 r;
    r.x = (uint)p[0] | ((uint)p[1] << 16);
    r.y = (uint)p[2] | ((uint)p[3] << 16);
    r.z = (uint)p[4] | ((uint)p[5] << 16);
    r.w = (uint)p[6] | ((uint)p[7] << 16);
    return r;
}

__device__ __forceinline__ void split8v(float4 a, float4 b, short8& hi, short8& lo) {
    float v[8] = {a.x, a.y, a.z, a.w, b.x, b.y, b.z, b.w};
    ushort h[8], l[8];
#pragma unroll
    for (int j = 0; j < 8; ++j) {
        h[j] = f2bf(v[j]);
        l[j] = f2bf(v[j] - __uint_as_float(((uint)h[j]) << 16));
    }
    uint4 H = pack8(h), L = pack8(l);
    hi = *(short8*)&H;
    lo = *(short8*)&L;
}

// ---------------------------------------------------------------------------
// K1+K2 fused: blocks 0..1535: MFMA embed, 16 tok x 64 out (one head),
// head-fastest for L2 x-reuse; 6 blocks/CU = 24 waves/CU (latency hiding).
// Blocks 1536..1562: W-prep + zeroing.
// Wave = 16tok x 16out frag; split-bf16 3-MFMA; 23.3 KB LDS.
// ---------------------------------------------------------------------------
__global__ __launch_bounds__(256) void k_embed_prep(const float* __restrict__ xs,
                                                    const float* __restrict__ ew,
                                                    const float* __restrict__ eb,
                                                    const float* __restrict__ nw,
                                                    float* __restrict__ Wn,
                                                    float* __restrict__ WnT,
                                                    float* __restrict__ r1inv,
                                                    float* __restrict__ zbase,
                                                    float* __restrict__ inp) {
    __shared__ __align__(16) unsigned char smem[23360];
    const int tid = threadIdx.x;
    const int bid = blockIdx.x;

    if (bid >= 1536) {   // ---- prep blocks ----
        const int pb = bid - 1536;
        if (pb == 0) {
            float* Wl = (float*)smem;   // [64][65] needs 16.6 KB < 23.3
            const int f = tid >> 2, q = tid & 3;
            float v[16];
            float s = 0.f;
#pragma unroll
            for (int i = 0; i < 16; ++i) { v[i] = nw[f * 64 + q * 16 + i]; s += v[i]; }
            s += __shfl_xor(s, 1, 64);
            s += __shfl_xor(s, 2, 64);
            const float inv = 1.f / fmaxf(s, 1e-20f);
#pragma unroll
            for (int i = 0; i < 16; ++i) {
                float w = v[i] * inv;
                Wn[f * 64 + q * 16 + i] = w;
                WnT[(q * 16 + i) * 64 + f] = w;
                Wl[f * 65 + q * 16 + i] = w;
            }
            __syncthreads();
            if (tid < 64) {
                float cs = 0.f;
                for (int ff = 0; ff < 64; ++ff) cs += Wl[ff * 65 + tid];
                float t = fmaxf(cs * (1.f / 64.f), 1e-6f);
                float S = t;
#pragma unroll
                for (int m = 1; m < 64; m <<= 1) S += __shfl_xor(S, m, 64);
                S = fmaxf(S, 1e-20f);
                r1inv[tid] = S / t;   // 1/rec1
            }
        } else {
            const int i = (pb - 1) * 1024 + tid * 4;
            if (i < 26112) {
                float4 z = make_float4(0.f, 0.f, 0.f, 0.f);
                *(float4*)(zbase + i) = z;
            }
        }
        return;
    }

    // ---- embed blocks: 16 tok x 64 out ----
    const int head = bid % 12;           // fastest -> 12 consecutive blocks share x-tile
    const int tok0 = (bid / 12) * 16;
    ushort* As_hi = (ushort*)smem;               // [16][72]
    ushort* As_lo = As_hi + 16 * 72;
    ushort* Bs_hi = As_lo + 16 * 72;             // [64][72]
    ushort* Bs_lo = Bs_hi + 64 * 72;
    float*  RS    = (float*)(Bs_lo + 64 * 72);   // [4][16]

    const int wv = tid >> 6, lane = tid & 63;
    const int nbase = wv * 16;           // this wave's 16-out quarter
    const int lm = lane & 15, lq = lane >> 4;

    floatx4 acc = (floatx4)0.f;

    // staging: A: 16 rows x 4 k/thread; B: 64 rows x 16 k/thread
    const int arow = tid >> 4, akc = (tid & 15) * 4;
    const int brow = tid >> 2, bkq = (tid & 3) * 16;
    const float* xrow = xs + (size_t)(tok0 + arow) * FIN + akc;
    const float* wrg  = ew + (size_t)(head * 64 + brow) * FIN + bkq;

    float4 pa, pb[4];
    pa = *(const float4*)(xrow);
#pragma unroll
    for (int c = 0; c < 4; ++c) pb[c] = *(const float4*)(wrg + c * 4);

    for (int kb = 0; kb < FIN; kb += 64) {
        __syncthreads();   // previous panel's frag reads done
        {
            float va[4] = {pa.x, pa.y, pa.z, pa.w};
            ushort ah[4], al[4];
#pragma unroll
            for (int j = 0; j < 4; ++j) {
                ah[j] = f2bf(va[j]);
                al[j] = f2bf(va[j] - __uint_as_float(((uint)ah[j]) << 16));
            }
            uint2 pAh, pAl;
            pAh.x = (uint)ah[0] | ((uint)ah[1] << 16);
            pAh.y = (uint)ah[2] | ((uint)ah[3] << 16);
            pAl.x = (uint)al[0] | ((uint)al[1] << 16);
            pAl.y = (uint)al[2] | ((uint)al[3] << 16);
            *(uint2*)&As_hi[arow * 72 + akc] = pAh;
            *(uint2*)&As_lo[arow * 72 + akc] = pAl;

            ushort bh[16], bl[16];
#pragma unroll
            for (int c4 = 0; c4 < 4; ++c4) {
                float vb[4] = {pb[c4].x, pb[c4].y, pb[c4].z, pb[c4].w};
#pragma unroll
                for (int j = 0; j < 4; ++j) {
                    ushort g = f2bf(vb[j]);
                    bh[c4 * 4 + j] = g;
                    bl[c4 * 4 + j] = f2bf(vb[j] - __uint_as_float(((uint)g) << 16));
                }
            }
            const int boff = brow * 72 + bkq;
            *(uint4*)&Bs_hi[boff]     = pack8(bh);
            *(uint4*)&Bs_hi[boff + 8] = pack8(bh + 8);
            *(uint4*)&Bs_lo[boff]     = pack8(bl);
            *(uint4*)&Bs_lo[boff + 8] = pack8(bl + 8);
        }
        __syncthreads();
        if (kb + 64 < FIN) {   // prefetch next panel during compute
            pa = *(const float4*)(xrow + kb + 64);
#pragma unroll
            for (int c = 0; c < 4; ++c) pb[c] = *(const float4*)(wrg + kb + 64 + c * 4);
        }
#pragma unroll
        for (int ch = 0; ch < 2; ++ch) {
            const int ko = ch * 32 + lq * 8;
            short8 ah = *(const short8*)&As_hi[lm * 72 + ko];
            short8 al = *(const short8*)&As_lo[lm * 72 + ko];
            short8 bh = *(const short8*)&Bs_hi[(nbase + lm) * 72 + ko];
            short8 bl = *(const short8*)&Bs_lo[(nbase + lm) * 72 + ko];
            acc = __builtin_amdgcn_mfma_f32_16x16x32_bf16(ah, bh, acc, 0, 0, 0);
            acc = __builtin_amdgcn_mfma_f32_16x16x32_bf16(al, bh, acc, 0, 0, 0);
            acc = __builtin_amdgcn_mfma_f32_16x16x32_bf16(ah, bl, acc, 0, 0, 0);
        }
    }

    // epilogue: bias, clamp, per-token l1norm over 64 outs (cross-wave via RS).
    // C/D: col = lane&15 = out-within-quarter, row = lq*4 + r = token.
    const float b0 = eb[head * 64 + nbase + lm];
    float xe[4];
    float rs[4];
#pragma unroll
    for (int r = 0; r < 4; ++r) {
        float e = fmaxf(acc[r] + b0, 1e-6f);
        xe[r] = e;
        float p = e;
        p += __shfl_xor(p, 1, 64);
        p += __shfl_xor(p, 2, 64);
        p += __shfl_xor(p, 4, 64);
        p += __shfl_xor(p, 8, 64);
        rs[r] = p;   // sum over this wave's 16 outs, per token
    }
    if (lm == 0) {
#pragma unroll
        for (int r = 0; r < 4; ++r) RS[wv * 16 + lq * 4 + r] = rs[r];
    }
    __syncthreads();
    const size_t obase = ((size_t)((tok0 >> 10) * 12 + head) * 1024 + (tok0 & 1023));
#pragma unroll
    for (int r = 0; r < 4; ++r) {
        const int m = lq * 4 + r;
        const float tot = RS[m] + RS[16 + m] + RS[32 + m] + RS[48 + m];
        const float inv = 1.f / fmaxf(tot, 1e-20f);
        inp[(obase + m) * 64 + nbase + lm] = xe[r] * inv;
    }
}

// ---------------------------------------------------------------------------
// K3 (MFMA): NNMF updates, 16 tokens per wave, 384 blocks x 4 waves.
// T is wave-private -> compiler-only wave_barrier instead of __syncthreads
// (per-wave DS ops execute in order on the LDS pipe).
// ---------------------------------------------------------------------------
__device__ __forceinline__ void mfma_matvec(const float srcC[4][4], float* T,
                                            int lm, int lq,
                                            const short8 Bh[4][2],
                                            const short8 Bl[4][2],
                                            floatx4 out[4]) {
    __builtin_amdgcn_wave_barrier();
#pragma unroll
    for (int nt = 0; nt < 4; ++nt)
#pragma unroll
        for (int r = 0; r < 4; ++r)
            T[(lq * 4 + r) * 68 + nt * 16 + lm] = srcC[nt][r];
    __builtin_amdgcn_wave_barrier();
    float4 a00 = *(const float4*)&T[lm * 68 + lq * 8];
    float4 a01 = *(const float4*)&T[lm * 68 + lq * 8 + 4];
    float4 a10 = *(const float4*)&T[lm * 68 + 32 + lq * 8];
    float4 a11 = *(const float4*)&T[lm * 68 + 32 + lq * 8 + 4];
    __builtin_amdgcn_wave_barrier();
    short8 A0h, A0l, A1h, A1l;
    split8v(a00, a01, A0h, A0l);
    split8v(a10, a11, A1h, A1l);
#pragma unroll
    for (int nt = 0; nt < 4; ++nt) {
        floatx4 acc = (floatx4)0.f;
        acc = __builtin_amdgcn_mfma_f32_16x16x32_bf16(A0h, Bh[nt][0], acc, 0, 0, 0);
        acc = __builtin_amdgcn_mfma_f32_16x16x32_bf16(A0l, Bh[nt][0], acc, 0, 0, 0);
        acc = __builtin_amdgcn_mfma_f32_16x16x32_bf16(A0h, Bl[nt][0], acc, 0, 0, 0);
        acc = __builtin_amdgcn_mfma_f32_16x16x32_bf16(A1h, Bh[nt][1], acc, 0, 0, 0);
        acc = __builtin_amdgcn_mfma_f32_16x16x32_bf16(A1l, Bh[nt][1], acc, 0, 0, 0);
        acc = __builtin_amdgcn_mfma_f32_16x16x32_bf16(A1h, Bl[nt][1], acc, 0, 0, 0);
        out[nt] = acc;
    }
}

__global__ __launch_bounds__(256) void k_nnmf(const float* __restrict__ inp,
                                              const float* __restrict__ Wn,
                                              const float* __restrict__ WnT,
                                              const float* __restrict__ r1inv,
                                              float* __restrict__ hout,
                                              float* __restrict__ hriout,
                                              float* __restrict__ mp0) {
    __shared__ float Tb[4][16 * 68];
    const int tid = threadIdx.x, wv = tid >> 6, lane = tid & 63;
    const int lm = lane & 15, lq = lane >> 4;
    float* T = Tb[wv];
    const int rowbase = blockIdx.x * 64 + wv * 16;

    short8 Bt_h[4][2], Bt_l[4][2], Bw_h[4][2], Bw_l[4][2];
#pragma unroll
    for (int nt = 0; nt < 4; ++nt)
#pragma unroll
        for (int kc = 0; kc < 2; ++kc) {
            const int idx = (nt * 16 + lm) * 64 + kc * 32 + lq * 8;
            split8v(*(const float4*)(WnT + idx), *(const float4*)(WnT + idx + 4),
                    Bt_h[nt][kc], Bt_l[nt][kc]);
            split8v(*(const float4*)(Wn + idx), *(const float4*)(Wn + idx + 4),
                    Bw_h[nt][kc], Bw_l[nt][kc]);
        }

    float inpC[4][4];
#pragma unroll
    for (int nt = 0; nt < 4; ++nt)
#pragma unroll
        for (int r = 0; r < 4; ++r)
            inpC[nt][r] = inp[(size_t)(rowbase + lq * 4 + r) * 64 + nt * 16 + lm];
    float r1c[4];
#pragma unroll
    for (int nt = 0; nt < 4; ++nt) r1c[nt] = r1inv[nt * 16 + lm];

    float hC[4][4], recC[4][4];
    {   // ---- iteration 1 (rec1 token-independent) ----
        float qC[4][4];
#pragma unroll
        for (int nt = 0; nt < 4; ++nt)
#pragma unroll
            for (int r = 0; r < 4; ++r) qC[nt][r] = inpC[nt][r] * r1c[nt];
        floatx4 u[4];
        mfma_matvec(qC, T, lm, lq, Bw_h, Bw_l, u);
#pragma unroll
        for (int nt = 0; nt < 4; ++nt)
#pragma unroll
            for (int r = 0; r < 4; ++r)
                hC[nt][r] = fmaxf(u[nt][r] * (1.f / 64.f), 1e-6f);
#pragma unroll
        for (int r = 0; r < 4; ++r) {
            float s = (hC[0][r] + hC[1][r]) + (hC[2][r] + hC[3][r]);
            s += __shfl_xor(s, 1, 64); s += __shfl_xor(s, 2, 64);
            s += __shfl_xor(s, 4, 64); s += __shfl_xor(s, 8, 64);
            const float inv = __builtin_amdgcn_rcpf(fmaxf(s, 1e-20f));
#pragma unroll
            for (int nt = 0; nt < 4; ++nt) hC[nt][r] *= inv;
        }
    }
#pragma unroll 1
    for (int it = 0; it < 2; ++it) {   // ---- iterations 2,3 (full) ----
        floatx4 t[4];
        mfma_matvec(hC, T, lm, lq, Bt_h, Bt_l, t);
        float tC[4][4], qC[4][4];
#pragma unroll
        for (int nt = 0; nt < 4; ++nt)
#pragma unroll
            for (int r = 0; r < 4; ++r) tC[nt][r] = fmaxf(t[nt][r], 1e-6f);
#pragma unroll
        for (int r = 0; r < 4; ++r) {
            float s = (tC[0][r] + tC[1][r]) + (tC[2][r] + tC[3][r]);
            s += __shfl_xor(s, 1, 64); s += __shfl_xor(s, 2, 64);
            s += __shfl_xor(s, 4, 64); s += __shfl_xor(s, 8, 64);
            s = fmaxf(s, 1e-20f);
            const float invS = __builtin_amdgcn_rcpf(s);
#pragma unroll
            for (int nt = 0; nt < 4; ++nt) {
                recC[nt][r] = tC[nt][r] * invS;
                qC[nt][r] = inpC[nt][r] * s * __builtin_amdgcn_rcpf(tC[nt][r]);
            }
        }
        floatx4 u[4];
        mfma_matvec(qC, T, lm, lq, Bw_h, Bw_l, u);
#pragma unroll
        for (int nt = 0; nt < 4; ++nt)
#pragma unroll
            for (int r = 0; r < 4; ++r)
                hC[nt][r] = fmaxf(hC[nt][r] * u[nt][r], 1e-6f);
#pragma unroll
        for (int r = 0; r < 4; ++r) {
            float s = (hC[0][r] + hC[1][r]) + (hC[2][r] + hC[3][r]);
            s += __shfl_xor(s, 1, 64); s += __shfl_xor(s, 2, 64);
            s += __shfl_xor(s, 4, 64); s += __shfl_xor(s, 8, 64);
            const float inv = __builtin_amdgcn_rcpf(fmaxf(s, 1e-20f));
#pragma unroll
            for (int nt = 0; nt < 4; ++nt) hC[nt][r] *= inv;
        }
    }
#pragma unroll
    for (int r = 0; r < 4; ++r) {
        float s = (hC[0][r] + hC[1][r]) + (hC[2][r] + hC[3][r]);
        s += __shfl_xor(s, 1, 64); s += __shfl_xor(s, 2, 64);
        s += __shfl_xor(s, 4, 64); s += __shfl_xor(s, 8, 64);
        const float inv = __builtin_amdgcn_rcpf(fmaxf(s, 1e-20f));
#pragma unroll
        for (int nt = 0; nt < 4; ++nt) hC[nt][r] *= inv;
    }
#pragma unroll
    for (int nt = 0; nt < 4; ++nt)
#pragma unroll
        for (int r = 0; r < 4; ++r) {
            const size_t o = (size_t)(rowbase + lq * 4 + r) * 64 + nt * 16 + lm;
            hout[o] = hC[nt][r];
            hriout[o] = recC[nt][r] * inpC[nt][r];
        }
    float hs[4];
#pragma unroll
    for (int nt = 0; nt < 4; ++nt) {
        float s = (hC[nt][0] + hC[nt][1]) + (hC[nt][2] + hC[nt][3]);
        s += __shfl_xor(s, 16, 64);
        s += __shfl_xor(s, 32, 64);
        hs[nt] = s;
    }
    float mvv = lq == 0 ? hs[0] : lq == 1 ? hs[1] : lq == 2 ? hs[2] : hs[3];
    atomicAdd(&mp0[(size_t)blockIdx.x * 64 + lq * 16 + lm], mvv);
}

// ---------------------------------------------------------------------------
// K4: one alpha iteration per launch, 384 blocks = (bh) x (64-o chunk).
// ---------------------------------------------------------------------------
__global__ __launch_bounds__(256) void k_alpha_step(const float* __restrict__ hin,
                                                    const float* __restrict__ hri,
                                                    const float* __restrict__ Wn,
                                                    const float* __restrict__ mp_in,
                                                    float* __restrict__ mp_out,
                                                    float* __restrict__ c,
                                                    float* __restrict__ M,
                                                    int it) {
    __shared__ float mred[4][64];
    __shared__ float mv[64];
    __shared__ float vv[64];
    __shared__ float cl[64];
    const int tid = threadIdx.x;
    const int bh = blockIdx.x >> 4;
    const int chunk = blockIdx.x & 15;
    const size_t rowbase = (size_t)bh * 1024 + chunk * 64;

    {
        int f = tid & 63, p = tid >> 6;
        float s = 0.f;
#pragma unroll
        for (int pp = 0; pp < 4; ++pp)
            s += mp_in[((size_t)bh * 16 + p * 4 + pp) * 64 + f];
        mred[p][f] = s;
    }
    __syncthreads();
    if (tid < 64)
        mv[tid] = (mred[0][tid] + mred[1][tid]) + (mred[2][tid] + mred[3][tid]);
    __syncthreads();
    {
        int d = tid & 63, qq = tid >> 6;
        float r = 0.f;
#pragma unroll
        for (int ff = 0; ff < 16; ++ff)
            r = fmaf(mv[qq * 16 + ff], Wn[(size_t)(qq * 16 + ff) * 64 + d], r);
        mred[qq][d] = r;
    }
    __syncthreads();
    if (tid < 64)
        vv[tid] = 1.f / (((mred[0][tid] + mred[1][tid]) + (mred[2][tid] + mred[3][tid])) + 1e-20f);
    __syncthreads();
    {
        int o = tid >> 2, dq = tid & 3;
        const float* rp = hri + (rowbase + o) * 64 + dq * 16;
        float dot = 0.f;
#pragma unroll
        for (int t4 = 0; t4 < 16; t4 += 4) {
            float4 r4 = *(const float4*)(rp + t4);
            dot = fmaf(r4.x, vv[dq * 16 + t4 + 0], dot);
            dot = fmaf(r4.y, vv[dq * 16 + t4 + 1], dot);
            dot = fmaf(r4.z, vv[dq * 16 + t4 + 2], dot);
            dot = fmaf(r4.w, vv[dq * 16 + t4 + 3], dot);
        }
        dot += __shfl_xor(dot, 1, 64);
        dot += __shfl_xor(dot, 2, 64);
        float cn = dot;
        if (it >= 2) cn *= c[rowbase + o];
        if (dq == 0) { c[rowbase + o] = cn; cl[o] = cn; }
    }
    __syncthreads();
    {
        const int f4 = (tid & 15) * 4, ogr = tid >> 4;
        float4 a = make_float4(0.f, 0.f, 0.f, 0.f);
#pragma unroll
        for (int oi = 0; oi < 4; ++oi) {
            int o = ogr * 4 + oi;
            float4 h4 = *(const float4*)(hin + (rowbase + o) * 64 + f4);
            float cv = cl[o];
            a.x = fmaf(h4.x, cv, a.x); a.y = fmaf(h4.y, cv, a.y);
            a.z = fmaf(h4.z, cv, a.z); a.w = fmaf(h4.w, cv, a.w);
        }
        a.x += __shfl_xor(a.x, 16, 64); a.y += __shfl_xor(a.y, 16, 64);
        a.z += __shfl_xor(a.z, 16, 64); a.w += __shfl_xor(a.w, 16, 64);
        a.x += __shfl_xor(a.x, 32, 64); a.y += __shfl_xor(a.y, 32, 64);
        a.z += __shfl_xor(a.z, 32, 64); a.w += __shfl_xor(a.w, 32, 64);
        const int w = tid >> 6;
        if ((tid & 63) < 16) *(float4*)&mred[w][(tid & 15) * 4] = a;
    }
    __syncthreads();
    if (tid < 64) {
        float s = (mred[0][tid] + mred[1][tid]) + (mred[2][tid] + mred[3][tid]);
        if (it == 3) atomicAdd(&M[(size_t)bh * 64 + tid], s);
        else mp_out[((size_t)bh * 16 + chunk) * 64 + tid] = s;
    }
}

// ---------------------------------------------------------------------------
// K5: out-projection + broadcast, 384 blocks = (b) x (12 out-seg) x (16 rowgrp).
// ---------------------------------------------------------------------------
__global__ __launch_bounds__(256) void k_projbcast(const float* __restrict__ M,
                                                   const float* __restrict__ ow,
                                                   const float* __restrict__ ob,
                                                   float* __restrict__ out) {
    __shared__ float Ml[768];
    __shared__ float ps[4][64];
    __shared__ float yseg[64];
    const int tid = threadIdx.x;
    const int b = blockIdx.x / 192;
    const int rem = blockIdx.x - b * 192;
    const int jt = rem >> 4, rg = rem & 15;
    for (int i = tid; i < 768; i += 256) Ml[i] = M[b * 768 + i];
    __syncthreads();
    const int jj = tid & 63, part = tid >> 6;
    const int j = jt * 64 + jj;
    const float* row = ow + (size_t)j * 768 + part * 192;
    float acc = 0.f;
    for (int t = 0; t < 192; t += 4) {
        float4 w4 = *(const float4*)(row + t);
        acc = fmaf(w4.x, Ml[part * 192 + t + 0], acc);
        acc = fmaf(w4.y, Ml[part * 192 + t + 1], acc);
        acc = fmaf(w4.z, Ml[part * 192 + t + 2], acc);
        acc = fmaf(w4.w, Ml[part * 192 + t + 3], acc);
    }
    ps[part][jj] = acc;
    __syncthreads();
    if (tid < 64)
        yseg[tid] = ps[0][tid] + ps[1][tid] + ps[2][tid] + ps[3][tid] + ob[jt * 64 + tid];
    __syncthreads();
    const int r0 = tid >> 2, c4 = (tid & 3) * 16;
    float4 v4[4];
#pragma unroll
    for (int q = 0; q < 4; ++q) v4[q] = *(const float4*)&yseg[c4 + q * 4];
    float* dst = out + ((size_t)(b * 1024 + rg * 64 + r0)) * 768 + jt * 64 + c4;
#pragma unroll
    for (int q = 0; q < 4; ++q) *(float4*)(dst + q * 4) = v4[q];
}

extern "C" void kernel_launch(void* const* d_in, const int* in_sizes, int n_in,
                              void* d_out, int out_size, void* d_ws, size_t ws_size,
                              hipStream_t stream) {
    const float* xs = (const float*)d_in[0];  // [2,1024,768]
    const float* ew = (const float*)d_in[1];  // [768,768]
    const float* eb = (const float*)d_in[2];  // [768]
    const float* nw = (const float*)d_in[3];  // [64,64]
    const float* ow = (const float*)d_in[4];  // [768,768]
    const float* ob = (const float*)d_in[5];  // [768]
    float* out = (float*)d_out;               // [2,1024,768]

    float* ws    = (float*)d_ws;
    float* inp   = ws;                 // 1572864
    float* h     = ws + 1572864;       // 1572864
    float* hri   = ws + 3145728;       // 1572864
    float* Wn    = ws + 4718592;       // 4096
    float* WnT   = ws + 4722688;       // 4096
    float* r1inv = ws + 4726784;       // 256
    float* mp0   = ws + 4727040;       // 24576 (atomic target, zeroed in-kernel)
    float* M     = ws + 4751616;       // 1536  (atomic target, zeroed in-kernel)
    float* mp1   = ws + 4753152;       // 24576
    float* mp2   = ws + 4777728;       // 24576
    float* c     = ws + 4802304;       // 24576

    k_embed_prep<<<1563, 256, 0, stream>>>(xs, ew, eb, nw, Wn, WnT, r1inv, mp0, inp);
    k_nnmf<<<384, 256, 0, stream>>>(inp, Wn, WnT, r1inv, h, hri, mp0);
    k_alpha_step<<<384, 256, 0, stream>>>(h, hri, Wn, mp0, mp1, c, M, 1);
    k_alpha_step<<<384, 256, 0, stream>>>(h, hri, Wn, mp1, mp2, c, M, 2);
    k_alpha_step<<<384, 256, 0, stream>>>(h, hri, Wn, mp2, mp1, c, M, 3);
    k_projbcast<<<384, 256, 0, stream>>>(M, ow, ob, out);
}

// Round 12
// 136.399 us; speedup vs baseline: 1.0580x; 1.0580x over previous
//
#include <hip/hip_runtime.h>

// Problem constants
#define B_  2
#define S_  1024
#define FIN 768
#define E_  768
#define H_  12
#define DH  64   // = FH = 64

typedef unsigned int uint;
typedef unsigned short ushort;
typedef __attribute__((ext_vector_type(8))) short short8;    // 8 bf16 (4 VGPRs)
typedef __attribute__((ext_vector_type(4))) float floatx4;   // MFMA acc

__device__ __forceinline__ ushort f2bf(float f) {   // RNE float->bf16 bits
    uint u = __float_as_uint(f);
    return (ushort)((u + 0x7fffu + ((u >> 16) & 1u)) >> 16);
}

__device__ __forceinline__ uint4 pack8(const ushort* p) {
    uint4 r;
    r.x = (uint)p[0] | ((uint)p[1] << 16);
    r.y = (uint)p[2] | ((uint)p[3] << 16);
    r.z = (uint)p[4] | ((uint)p[5] << 16);
    r.w = (uint)p[6] | ((uint)p[7] << 16);
    return r;
}

__device__ __forceinline__ void split8v(float4 a, float4 b, short8& hi, short8& lo) {
    float v[8] = {a.x, a.y, a.z, a.w, b.x, b.y, b.z, b.w};
    ushort h[8], l[8];
#pragma unroll
    for (int j = 0; j < 8; ++j) {
        h[j] = f2bf(v[j]);
        l[j] = f2bf(v[j] - __uint_as_float(((uint)h[j]) << 16));
    }
    uint4 H = pack8(h), L = pack8(l);
    hi = *(short8*)&H;
    lo = *(short8*)&L;
}

// ---------------------------------------------------------------------------
// K1+K2 fused (R10-exact): blocks 0..767: MFMA embed (32 tok x 64 out = 1 head;
// head-fastest for L2 x-reuse). Blocks 768..794: W-prep + zeroing.
// Split-bf16 (hi+lo) in-kernel conversion, 3 MFMA/tile-pair.
// 4 waves: wave = 16tok x 32out (1x2 frags of 16x16x32). 27.9 KB LDS.
// ---------------------------------------------------------------------------
__global__ __launch_bounds__(256) void k_embed_prep(const float* __restrict__ xs,
                                                    const float* __restrict__ ew,
                                                    const float* __restrict__ eb,
                                                    const float* __restrict__ nw,
                                                    float* __restrict__ Wn,
                                                    float* __restrict__ WnT,
                                                    float* __restrict__ r1inv,
                                                    float* __restrict__ zbase,
                                                    float* __restrict__ inp) {
    __shared__ __align__(16) unsigned char smem[28160];
    const int tid = threadIdx.x;
    const int bid = blockIdx.x;

    if (bid >= 768) {   // ---- prep blocks ----
        const int pb = bid - 768;
        if (pb == 0) {
            float* Wl = (float*)smem;   // [64][65]
            const int f = tid >> 2, q = tid & 3;
            float v[16];
            float s = 0.f;
#pragma unroll
            for (int i = 0; i < 16; ++i) { v[i] = nw[f * 64 + q * 16 + i]; s += v[i]; }
            s += __shfl_xor(s, 1, 64);
            s += __shfl_xor(s, 2, 64);
            const float inv = 1.f / fmaxf(s, 1e-20f);
#pragma unroll
            for (int i = 0; i < 16; ++i) {
                float w = v[i] * inv;
                Wn[f * 64 + q * 16 + i] = w;
                WnT[(q * 16 + i) * 64 + f] = w;
                Wl[f * 65 + q * 16 + i] = w;
            }
            __syncthreads();
            if (tid < 64) {
                float cs = 0.f;
                for (int ff = 0; ff < 64; ++ff) cs += Wl[ff * 65 + tid];
                float t = fmaxf(cs * (1.f / 64.f), 1e-6f);
                float S = t;
#pragma unroll
                for (int m = 1; m < 64; m <<= 1) S += __shfl_xor(S, m, 64);
                S = fmaxf(S, 1e-20f);
                r1inv[tid] = S / t;   // 1/rec1
            }
        } else {
            const int i = (pb - 1) * 1024 + tid * 4;
            if (i < 26112) {
                float4 z = make_float4(0.f, 0.f, 0.f, 0.f);
                *(float4*)(zbase + i) = z;
            }
        }
        return;
    }

    // ---- embed blocks ----
    const int head = bid % 12;           // fastest -> consecutive blocks share x-tile
    const int tok0 = (bid / 12) * 32;
    ushort* As_hi = (ushort*)smem;               // [32][72]
    ushort* As_lo = As_hi + 32 * 72;
    ushort* Bs_hi = As_lo + 32 * 72;             // [64][72]
    ushort* Bs_lo = Bs_hi + 64 * 72;
    float*  RS    = (float*)(Bs_lo + 64 * 72);   // [2][32]

    const int wv = tid >> 6, lane = tid & 63;
    const int mbase = (wv >> 1) * 16;    // 16-token frag row
    const int nbase = (wv & 1) * 32;     // 32-out half
    const int lm = lane & 15, lq = lane >> 4;

    floatx4 acc[2];
    acc[0] = (floatx4)0.f;
    acc[1] = (floatx4)0.f;

    // staging assignment
    const int arow = tid >> 3, akc = (tid & 7) * 8;    // A: 32 rows x 8 k
    const int brow = tid >> 2, bkq = (tid & 3) * 16;   // B: 64 rows x 16 k
    const float* xrow = xs + (size_t)(tok0 + arow) * FIN + akc;
    const float* wrg  = ew + (size_t)(head * 64 + brow) * FIN + bkq;

    float4 pa[2], pb[4];
#pragma unroll
    for (int c = 0; c < 2; ++c) pa[c] = *(const float4*)(xrow + c * 4);
#pragma unroll
    for (int c = 0; c < 4; ++c) pb[c] = *(const float4*)(wrg + c * 4);

    for (int kb = 0; kb < FIN; kb += 64) {
        __syncthreads();   // previous panel's frag reads done
        {
            ushort ah[8], al[8], bh[16], bl[16];
            float va[8] = {pa[0].x, pa[0].y, pa[0].z, pa[0].w,
                           pa[1].x, pa[1].y, pa[1].z, pa[1].w};
#pragma unroll
            for (int j = 0; j < 8; ++j) {
                ah[j] = f2bf(va[j]);
                al[j] = f2bf(va[j] - __uint_as_float(((uint)ah[j]) << 16));
            }
#pragma unroll
            for (int c4 = 0; c4 < 4; ++c4) {
                float vb[4] = {pb[c4].x, pb[c4].y, pb[c4].z, pb[c4].w};
#pragma unroll
                for (int j = 0; j < 4; ++j) {
                    ushort g = f2bf(vb[j]);
                    bh[c4 * 4 + j] = g;
                    bl[c4 * 4 + j] = f2bf(vb[j] - __uint_as_float(((uint)g) << 16));
                }
            }
            const int aoff = arow * 72 + akc;
            *(uint4*)&As_hi[aoff] = pack8(ah);
            *(uint4*)&As_lo[aoff] = pack8(al);
            const int boff = brow * 72 + bkq;
            *(uint4*)&Bs_hi[boff]     = pack8(bh);
            *(uint4*)&Bs_hi[boff + 8] = pack8(bh + 8);
            *(uint4*)&Bs_lo[boff]     = pack8(bl);
            *(uint4*)&Bs_lo[boff + 8] = pack8(bl + 8);
        }
        __syncthreads();
        if (kb + 64 < FIN) {   // prefetch next panel during compute
#pragma unroll
            for (int c = 0; c < 2; ++c) pa[c] = *(const float4*)(xrow + kb + 64 + c * 4);
#pragma unroll
            for (int c = 0; c < 4; ++c) pb[c] = *(const float4*)(wrg + kb + 64 + c * 4);
        }
#pragma unroll
        for (int ch = 0; ch < 2; ++ch) {
            const int ko = ch * 32 + lq * 8;
            short8 ah = *(const short8*)&As_hi[(mbase + lm) * 72 + ko];
            short8 al = *(const short8*)&As_lo[(mbase + lm) * 72 + ko];
#pragma unroll
            for (int ti = 0; ti < 2; ++ti) {
                short8 bh = *(const short8*)&Bs_hi[(nbase + ti * 16 + lm) * 72 + ko];
                short8 bl = *(const short8*)&Bs_lo[(nbase + ti * 16 + lm) * 72 + ko];
                acc[ti] = __builtin_amdgcn_mfma_f32_16x16x32_bf16(ah, bh, acc[ti], 0, 0, 0);
                acc[ti] = __builtin_amdgcn_mfma_f32_16x16x32_bf16(al, bh, acc[ti], 0, 0, 0);
                acc[ti] = __builtin_amdgcn_mfma_f32_16x16x32_bf16(ah, bl, acc[ti], 0, 0, 0);
            }
        }
    }

    // epilogue: bias, clamp, per-token l1norm over 64 outs, store.
    const float b0 = eb[head * 64 + nbase + lm];
    const float b1 = eb[head * 64 + nbase + 16 + lm];
    float xe[2][4];
    float rs[4];
#pragma unroll
    for (int r = 0; r < 4; ++r) {
        float e0 = fmaxf(acc[0][r] + b0, 1e-6f);
        float e1 = fmaxf(acc[1][r] + b1, 1e-6f);
        xe[0][r] = e0; xe[1][r] = e1;
        float p = e0 + e1;
        p += __shfl_xor(p, 1, 64);
        p += __shfl_xor(p, 2, 64);
        p += __shfl_xor(p, 4, 64);
        p += __shfl_xor(p, 8, 64);
        rs[r] = p;
    }
    if (lm == 0) {
#pragma unroll
        for (int r = 0; r < 4; ++r)
            RS[(wv & 1) * 32 + mbase + lq * 4 + r] = rs[r];
    }
    __syncthreads();
    const size_t obase = ((size_t)((tok0 >> 10) * 12 + head) * 1024 + (tok0 & 1023));
#pragma unroll
    for (int r = 0; r < 4; ++r) {
        const int m = mbase + lq * 4 + r;
        const float inv = 1.f / fmaxf(RS[m] + RS[32 + m], 1e-20f);
        float* op = inp + (obase + m) * 64;
        op[nbase + lm]      = xe[0][r] * inv;
        op[nbase + 16 + lm] = xe[1][r] * inv;
    }
}

// ---------------------------------------------------------------------------
// K3 (MFMA): NNMF updates, 16 tokens per wave, 384 blocks x 4 waves.
// T is wave-private -> wave_barrier only (no block syncthreads in matvec);
// per-wave DS ops execute in order, compiler inserts lgkmcnt waits.
// ---------------------------------------------------------------------------
__device__ __forceinline__ void mfma_matvec(const float srcC[4][4], float* T,
                                            int lm, int lq,
                                            const short8 Bh[4][2],
                                            const short8 Bl[4][2],
                                            floatx4 out[4]) {
    __builtin_amdgcn_wave_barrier();
#pragma unroll
    for (int nt = 0; nt < 4; ++nt)
#pragma unroll
        for (int r = 0; r < 4; ++r)
            T[(lq * 4 + r) * 68 + nt * 16 + lm] = srcC[nt][r];
    __builtin_amdgcn_wave_barrier();
    float4 a00 = *(const float4*)&T[lm * 68 + lq * 8];
    float4 a01 = *(const float4*)&T[lm * 68 + lq * 8 + 4];
    float4 a10 = *(const float4*)&T[lm * 68 + 32 + lq * 8];
    float4 a11 = *(const float4*)&T[lm * 68 + 32 + lq * 8 + 4];
    __builtin_amdgcn_wave_barrier();
    short8 A0h, A0l, A1h, A1l;
    split8v(a00, a01, A0h, A0l);
    split8v(a10, a11, A1h, A1l);
#pragma unroll
    for (int nt = 0; nt < 4; ++nt) {
        floatx4 acc = (floatx4)0.f;
        acc = __builtin_amdgcn_mfma_f32_16x16x32_bf16(A0h, Bh[nt][0], acc, 0, 0, 0);
        acc = __builtin_amdgcn_mfma_f32_16x16x32_bf16(A0l, Bh[nt][0], acc, 0, 0, 0);
        acc = __builtin_amdgcn_mfma_f32_16x16x32_bf16(A0h, Bl[nt][0], acc, 0, 0, 0);
        acc = __builtin_amdgcn_mfma_f32_16x16x32_bf16(A1h, Bh[nt][1], acc, 0, 0, 0);
        acc = __builtin_amdgcn_mfma_f32_16x16x32_bf16(A1l, Bh[nt][1], acc, 0, 0, 0);
        acc = __builtin_amdgcn_mfma_f32_16x16x32_bf16(A1h, Bl[nt][1], acc, 0, 0, 0);
        out[nt] = acc;
    }
}

__global__ __launch_bounds__(256) void k_nnmf(const float* __restrict__ inp,
                                              const float* __restrict__ Wn,
                                              const float* __restrict__ WnT,
                                              const float* __restrict__ r1inv,
                                              float* __restrict__ hout,
                                              float* __restrict__ hriout,
                                              float* __restrict__ mp0) {
    __shared__ float Tb[4][16 * 68];
    const int tid = threadIdx.x, wv = tid >> 6, lane = tid & 63;
    const int lm = lane & 15, lq = lane >> 4;
    float* T = Tb[wv];
    const int rowbase = blockIdx.x * 64 + wv * 16;

    short8 Bt_h[4][2], Bt_l[4][2], Bw_h[4][2], Bw_l[4][2];
#pragma unroll
    for (int nt = 0; nt < 4; ++nt)
#pragma unroll
        for (int kc = 0; kc < 2; ++kc) {
            const int idx = (nt * 16 + lm) * 64 + kc * 32 + lq * 8;
            split8v(*(const float4*)(WnT + idx), *(const float4*)(WnT + idx + 4),
                    Bt_h[nt][kc], Bt_l[nt][kc]);
            split8v(*(const float4*)(Wn + idx), *(const float4*)(Wn + idx + 4),
                    Bw_h[nt][kc], Bw_l[nt][kc]);
        }

    float inpC[4][4];
#pragma unroll
    for (int nt = 0; nt < 4; ++nt)
#pragma unroll
        for (int r = 0; r < 4; ++r)
            inpC[nt][r] = inp[(size_t)(rowbase + lq * 4 + r) * 64 + nt * 16 + lm];
    float r1c[4];
#pragma unroll
    for (int nt = 0; nt < 4; ++nt) r1c[nt] = r1inv[nt * 16 + lm];

    float hC[4][4], recC[4][4];
    {   // ---- iteration 1 (rec1 token-independent) ----
        float qC[4][4];
#pragma unroll
        for (int nt = 0; nt < 4; ++nt)
#pragma unroll
            for (int r = 0; r < 4; ++r) qC[nt][r] = inpC[nt][r] * r1c[nt];
        floatx4 u[4];
        mfma_matvec(qC, T, lm, lq, Bw_h, Bw_l, u);
#pragma unroll
        for (int nt = 0; nt < 4; ++nt)
#pragma unroll
            for (int r = 0; r < 4; ++r)
                hC[nt][r] = fmaxf(u[nt][r] * (1.f / 64.f), 1e-6f);
#pragma unroll
        for (int r = 0; r < 4; ++r) {
            float s = (hC[0][r] + hC[1][r]) + (hC[2][r] + hC[3][r]);
            s += __shfl_xor(s, 1, 64); s += __shfl_xor(s, 2, 64);
            s += __shfl_xor(s, 4, 64); s += __shfl_xor(s, 8, 64);
            const float inv = __builtin_amdgcn_rcpf(fmaxf(s, 1e-20f));
#pragma unroll
            for (int nt = 0; nt < 4; ++nt) hC[nt][r] *= inv;
        }
    }
#pragma unroll 1
    for (int it = 0; it < 2; ++it) {   // ---- iterations 2,3 (full) ----
        floatx4 t[4];
        mfma_matvec(hC, T, lm, lq, Bt_h, Bt_l, t);
        float tC[4][4], qC[4][4];
#pragma unroll
        for (int nt = 0; nt < 4; ++nt)
#pragma unroll
            for (int r = 0; r < 4; ++r) tC[nt][r] = fmaxf(t[nt][r], 1e-6f);
#pragma unroll
        for (int r = 0; r < 4; ++r) {
            float s = (tC[0][r] + tC[1][r]) + (tC[2][r] + tC[3][r]);
            s += __shfl_xor(s, 1, 64); s += __shfl_xor(s, 2, 64);
            s += __shfl_xor(s, 4, 64); s += __shfl_xor(s, 8, 64);
            s = fmaxf(s, 1e-20f);
            const float invS = __builtin_amdgcn_rcpf(s);
#pragma unroll
            for (int nt = 0; nt < 4; ++nt) {
                recC[nt][r] = tC[nt][r] * invS;
                qC[nt][r] = inpC[nt][r] * s * __builtin_amdgcn_rcpf(tC[nt][r]);
            }
        }
        floatx4 u[4];
        mfma_matvec(qC, T, lm, lq, Bw_h, Bw_l, u);
#pragma unroll
        for (int nt = 0; nt < 4; ++nt)
#pragma unroll
            for (int r = 0; r < 4; ++r)
                hC[nt][r] = fmaxf(hC[nt][r] * u[nt][r], 1e-6f);
#pragma unroll
        for (int r = 0; r < 4; ++r) {
            float s = (hC[0][r] + hC[1][r]) + (hC[2][r] + hC[3][r]);
            s += __shfl_xor(s, 1, 64); s += __shfl_xor(s, 2, 64);
            s += __shfl_xor(s, 4, 64); s += __shfl_xor(s, 8, 64);
            const float inv = __builtin_amdgcn_rcpf(fmaxf(s, 1e-20f));
#pragma unroll
            for (int nt = 0; nt < 4; ++nt) hC[nt][r] *= inv;
        }
    }
#pragma unroll
    for (int r = 0; r < 4; ++r) {
        float s = (hC[0][r] + hC[1][r]) + (hC[2][r] + hC[3][r]);
        s += __shfl_xor(s, 1, 64); s += __shfl_xor(s, 2, 64);
        s += __shfl_xor(s, 4, 64); s += __shfl_xor(s, 8, 64);
        const float inv = __builtin_amdgcn_rcpf(fmaxf(s, 1e-20f));
#pragma unroll
        for (int nt = 0; nt < 4; ++nt) hC[nt][r] *= inv;
    }
#pragma unroll
    for (int nt = 0; nt < 4; ++nt)
#pragma unroll
        for (int r = 0; r < 4; ++r) {
            const size_t o = (size_t)(rowbase + lq * 4 + r) * 64 + nt * 16 + lm;
            hout[o] = hC[nt][r];
            hriout[o] = recC[nt][r] * inpC[nt][r];
        }
    float hs[4];
#pragma unroll
    for (int nt = 0; nt < 4; ++nt) {
        float s = (hC[nt][0] + hC[nt][1]) + (hC[nt][2] + hC[nt][3]);
        s += __shfl_xor(s, 16, 64);
        s += __shfl_xor(s, 32, 64);
        hs[nt] = s;
    }
    float mvv = lq == 0 ? hs[0] : lq == 1 ? hs[1] : lq == 2 ? hs[2] : hs[3];
    atomicAdd(&mp0[(size_t)blockIdx.x * 64 + lq * 16 + lm], mvv);
}

// ---------------------------------------------------------------------------
// K4: one alpha iteration per launch, 384 blocks = (bh) x (64-o chunk).
// ---------------------------------------------------------------------------
__global__ __launch_bounds__(256) void k_alpha_step(const float* __restrict__ hin,
                                                    const float* __restrict__ hri,
                                                    const float* __restrict__ Wn,
                                                    const float* __restrict__ mp_in,
                                                    float* __restrict__ mp_out,
                                                    float* __restrict__ c,
                                                    float* __restrict__ M,
                                                    int it) {
    __shared__ float mred[4][64];
    __shared__ float mv[64];
    __shared__ float vv[64];
    __shared__ float cl[64];
    const int tid = threadIdx.x;
    const int bh = blockIdx.x >> 4;
    const int chunk = blockIdx.x & 15;
    const size_t rowbase = (size_t)bh * 1024 + chunk * 64;

    {
        int f = tid & 63, p = tid >> 6;
        float s = 0.f;
#pragma unroll
        for (int pp = 0; pp < 4; ++pp)
            s += mp_in[((size_t)bh * 16 + p * 4 + pp) * 64 + f];
        mred[p][f] = s;
    }
    __syncthreads();
    if (tid < 64)
        mv[tid] = (mred[0][tid] + mred[1][tid]) + (mred[2][tid] + mred[3][tid]);
    __syncthreads();
    {
        int d = tid & 63, qq = tid >> 6;
        float r = 0.f;
#pragma unroll
        for (int ff = 0; ff < 16; ++ff)
            r = fmaf(mv[qq * 16 + ff], Wn[(size_t)(qq * 16 + ff) * 64 + d], r);
        mred[qq][d] = r;
    }
    __syncthreads();
    if (tid < 64)
        vv[tid] = 1.f / (((mred[0][tid] + mred[1][tid]) + (mred[2][tid] + mred[3][tid])) + 1e-20f);
    __syncthreads();
    {
        int o = tid >> 2, dq = tid & 3;
        const float* rp = hri + (rowbase + o) * 64 + dq * 16;
        float dot = 0.f;
#pragma unroll
        for (int t4 = 0; t4 < 16; t4 += 4) {
            float4 r4 = *(const float4*)(rp + t4);
            dot = fmaf(r4.x, vv[dq * 16 + t4 + 0], dot);
            dot = fmaf(r4.y, vv[dq * 16 + t4 + 1], dot);
            dot = fmaf(r4.z, vv[dq * 16 + t4 + 2], dot);
            dot = fmaf(r4.w, vv[dq * 16 + t4 + 3], dot);
        }
        dot += __shfl_xor(dot, 1, 64);
        dot += __shfl_xor(dot, 2, 64);
        float cn = dot;
        if (it >= 2) cn *= c[rowbase + o];
        if (dq == 0) { c[rowbase + o] = cn; cl[o] = cn; }
    }
    __syncthreads();
    {
        const int f4 = (tid & 15) * 4, ogr = tid >> 4;
        float4 a = make_float4(0.f, 0.f, 0.f, 0.f);
#pragma unroll
        for (int oi = 0; oi < 4; ++oi) {
            int o = ogr * 4 + oi;
            float4 h4 = *(const float4*)(hin + (rowbase + o) * 64 + f4);
            float cv = cl[o];
            a.x = fmaf(h4.x, cv, a.x); a.y = fmaf(h4.y, cv, a.y);
            a.z = fmaf(h4.z, cv, a.z); a.w = fmaf(h4.w, cv, a.w);
        }
        a.x += __shfl_xor(a.x, 16, 64); a.y += __shfl_xor(a.y, 16, 64);
        a.z += __shfl_xor(a.z, 16, 64); a.w += __shfl_xor(a.w, 16, 64);
        a.x += __shfl_xor(a.x, 32, 64); a.y += __shfl_xor(a.y, 32, 64);
        a.z += __shfl_xor(a.z, 32, 64); a.w += __shfl_xor(a.w, 32, 64);
        const int w = tid >> 6;
        if ((tid & 63) < 16) *(float4*)&mred[w][(tid & 15) * 4] = a;
    }
    __syncthreads();
    if (tid < 64) {
        float s = (mred[0][tid] + mred[1][tid]) + (mred[2][tid] + mred[3][tid]);
        if (it == 3) atomicAdd(&M[(size_t)bh * 64 + tid], s);
        else mp_out[((size_t)bh * 16 + chunk) * 64 + tid] = s;
    }
}

// ---------------------------------------------------------------------------
// K5: out-projection + broadcast, 384 blocks = (b) x (12 out-seg) x (16 rowgrp).
// ---------------------------------------------------------------------------
__global__ __launch_bounds__(256) void k_projbcast(const float* __restrict__ M,
                                                   const float* __restrict__ ow,
                                                   const float* __restrict__ ob,
                                                   float* __restrict__ out) {
    __shared__ float Ml[768];
    __shared__ float ps[4][64];
    __shared__ float yseg[64];
    const int tid = threadIdx.x;
    const int b = blockIdx.x / 192;
    const int rem = blockIdx.x - b * 192;
    const int jt = rem >> 4, rg = rem & 15;
    for (int i = tid; i < 768; i += 256) Ml[i] = M[b * 768 + i];
    __syncthreads();
    const int jj = tid & 63, part = tid >> 6;
    const int j = jt * 64 + jj;
    const float* row = ow + (size_t)j * 768 + part * 192;
    float acc = 0.f;
    for (int t = 0; t < 192; t += 4) {
        float4 w4 = *(const float4*)(row + t);
        acc = fmaf(w4.x, Ml[part * 192 + t + 0], acc);
        acc = fmaf(w4.y, Ml[part * 192 + t + 1], acc);
        acc = fmaf(w4.z, Ml[part * 192 + t + 2], acc);
        acc = fmaf(w4.w, Ml[part * 192 + t + 3], acc);
    }
    ps[part][jj] = acc;
    __syncthreads();
    if (tid < 64)
        yseg[tid] = ps[0][tid] + ps[1][tid] + ps[2][tid] + ps[3][tid] + ob[jt * 64 + tid];
    __syncthreads();
    const int r0 = tid >> 2, c4 = (tid & 3) * 16;
    float4 v4[4];
#pragma unroll
    for (int q = 0; q < 4; ++q) v4[q] = *(const float4*)&yseg[c4 + q * 4];
    float* dst = out + ((size_t)(b * 1024 + rg * 64 + r0)) * 768 + jt * 64 + c4;
#pragma unroll
    for (int q = 0; q < 4; ++q) *(float4*)(dst + q * 4) = v4[q];
}

extern "C" void kernel_launch(void* const* d_in, const int* in_sizes, int n_in,
                              void* d_out, int out_size, void* d_ws, size_t ws_size,
                              hipStream_t stream) {
    const float* xs = (const float*)d_in[0];  // [2,1024,768]
    const float* ew = (const float*)d_in[1];  // [768,768]
    const float* eb = (const float*)d_in[2];  // [768]
    const float* nw = (const float*)d_in[3];  // [64,64]
    const float* ow = (const float*)d_in[4];  // [768,768]
    const float* ob = (const float*)d_in[5];  // [768]
    float* out = (float*)d_out;               // [2,1024,768]

    float* ws    = (float*)d_ws;
    float* inp   = ws;                 // 1572864
    float* h     = ws + 1572864;       // 1572864
    float* hri   = ws + 3145728;       // 1572864
    float* Wn    = ws + 4718592;       // 4096
    float* WnT   = ws + 4722688;       // 4096
    float* r1inv = ws + 4726784;       // 256
    float* mp0   = ws + 4727040;       // 24576 (atomic target, zeroed in-kernel)
    float* M     = ws + 4751616;       // 1536  (atomic target, zeroed in-kernel)
    float* mp1   = ws + 4753152;       // 24576
    float* mp2   = ws + 4777728;       // 24576
    float* c     = ws + 4802304;       // 24576

    k_embed_prep<<<795, 256, 0, stream>>>(xs, ew, eb, nw, Wn, WnT, r1inv, mp0, inp);
    k_nnmf<<<384, 256, 0, stream>>>(inp, Wn, WnT, r1inv, h, hri, mp0);
    k_alpha_step<<<384, 256, 0, stream>>>(h, hri, Wn, mp0, mp1, c, M, 1);
    k_alpha_step<<<384, 256, 0, stream>>>(h, hri, Wn, mp1, mp2, c, M, 2);
    k_alpha_step<<<384, 256, 0, stream>>>(h, hri, Wn, mp2, mp1, c, M, 3);
    k_projbcast<<<384, 256, 0, stream>>>(M, ow, ob, out);
}

// Round 13
// 131.669 us; speedup vs baseline: 1.0960x; 1.0359x over previous
//
#include <hip/hip_runtime.h>

// Problem constants
#define B_  2
#define S_  1024
#define FIN 768
#define E_  768
#define H_  12
#define DH  64   // = FH = 64

typedef unsigned int uint;
typedef unsigned short ushort;
typedef __attribute__((ext_vector_type(8))) short short8;    // 8 bf16 (4 VGPRs)
typedef __attribute__((ext_vector_type(4))) float floatx4;   // MFMA acc

__device__ __forceinline__ ushort f2bf(float f) {   // RNE float->bf16 bits
    uint u = __float_as_uint(f);
    return (ushort)((u + 0x7fffu + ((u >> 16) & 1u)) >> 16);
}

__device__ __forceinline__ uint4 pack8(const ushort* p) {
    uint4 r;
    r.x = (uint)p[0] | ((uint)p[1] << 16);
    r.y = (uint)p[2] | ((uint)p[3] << 16);
    r.z = (uint)p[4] | ((uint)p[5] << 16);
    r.w = (uint)p[6] | ((uint)p[7] << 16);
    return r;
}

__device__ __forceinline__ void split8v(float4 a, float4 b, short8& hi, short8& lo) {
    float v[8] = {a.x, a.y, a.z, a.w, b.x, b.y, b.z, b.w};
    ushort h[8], l[8];
#pragma unroll
    for (int j = 0; j < 8; ++j) {
        h[j] = f2bf(v[j]);
        l[j] = f2bf(v[j] - __uint_as_float(((uint)h[j]) << 16));
    }
    uint4 H = pack8(h), L = pack8(l);
    hi = *(short8*)&H;
    lo = *(short8*)&L;
}

// ---------------------------------------------------------------------------
// K1+K2 fused (R10-exact): blocks 0..767: MFMA embed (32 tok x 64 out = 1 head;
// head-fastest for L2 x-reuse). Blocks 768..794: W-prep + zeroing.
// Split-bf16 (hi+lo) in-kernel conversion, 3 MFMA/tile-pair.
// 4 waves: wave = 16tok x 32out (1x2 frags of 16x16x32). 27.9 KB LDS.
// ---------------------------------------------------------------------------
__global__ __launch_bounds__(256) void k_embed_prep(const float* __restrict__ xs,
                                                    const float* __restrict__ ew,
                                                    const float* __restrict__ eb,
                                                    const float* __restrict__ nw,
                                                    float* __restrict__ Wn,
                                                    float* __restrict__ WnT,
                                                    float* __restrict__ r1inv,
                                                    float* __restrict__ zbase,
                                                    float* __restrict__ inp) {
    __shared__ __align__(16) unsigned char smem[28160];
    const int tid = threadIdx.x;
    const int bid = blockIdx.x;

    if (bid >= 768) {   // ---- prep blocks ----
        const int pb = bid - 768;
        if (pb == 0) {
            float* Wl = (float*)smem;   // [64][65]
            const int f = tid >> 2, q = tid & 3;
            float v[16];
            float s = 0.f;
#pragma unroll
            for (int i = 0; i < 16; ++i) { v[i] = nw[f * 64 + q * 16 + i]; s += v[i]; }
            s += __shfl_xor(s, 1, 64);
            s += __shfl_xor(s, 2, 64);
            const float inv = 1.f / fmaxf(s, 1e-20f);
#pragma unroll
            for (int i = 0; i < 16; ++i) {
                float w = v[i] * inv;
                Wn[f * 64 + q * 16 + i] = w;
                WnT[(q * 16 + i) * 64 + f] = w;
                Wl[f * 65 + q * 16 + i] = w;
            }
            __syncthreads();
            if (tid < 64) {
                float cs = 0.f;
                for (int ff = 0; ff < 64; ++ff) cs += Wl[ff * 65 + tid];
                float t = fmaxf(cs * (1.f / 64.f), 1e-6f);
                float S = t;
#pragma unroll
                for (int m = 1; m < 64; m <<= 1) S += __shfl_xor(S, m, 64);
                S = fmaxf(S, 1e-20f);
                r1inv[tid] = S / t;   // 1/rec1
            }
        } else {
            const int i = (pb - 1) * 1024 + tid * 4;
            if (i < 26112) {
                float4 z = make_float4(0.f, 0.f, 0.f, 0.f);
                *(float4*)(zbase + i) = z;
            }
        }
        return;
    }

    // ---- embed blocks ----
    const int head = bid % 12;           // fastest -> consecutive blocks share x-tile
    const int tok0 = (bid / 12) * 32;
    ushort* As_hi = (ushort*)smem;               // [32][72]
    ushort* As_lo = As_hi + 32 * 72;
    ushort* Bs_hi = As_lo + 32 * 72;             // [64][72]
    ushort* Bs_lo = Bs_hi + 64 * 72;
    float*  RS    = (float*)(Bs_lo + 64 * 72);   // [2][32]

    const int wv = tid >> 6, lane = tid & 63;
    const int mbase = (wv >> 1) * 16;    // 16-token frag row
    const int nbase = (wv & 1) * 32;     // 32-out half
    const int lm = lane & 15, lq = lane >> 4;

    floatx4 acc[2];
    acc[0] = (floatx4)0.f;
    acc[1] = (floatx4)0.f;

    // staging assignment
    const int arow = tid >> 3, akc = (tid & 7) * 8;    // A: 32 rows x 8 k
    const int brow = tid >> 2, bkq = (tid & 3) * 16;   // B: 64 rows x 16 k
    const float* xrow = xs + (size_t)(tok0 + arow) * FIN + akc;
    const float* wrg  = ew + (size_t)(head * 64 + brow) * FIN + bkq;

    float4 pa[2], pb[4];
#pragma unroll
    for (int c = 0; c < 2; ++c) pa[c] = *(const float4*)(xrow + c * 4);
#pragma unroll
    for (int c = 0; c < 4; ++c) pb[c] = *(const float4*)(wrg + c * 4);

    for (int kb = 0; kb < FIN; kb += 64) {
        __syncthreads();   // previous panel's frag reads done
        {
            ushort ah[8], al[8], bh[16], bl[16];
            float va[8] = {pa[0].x, pa[0].y, pa[0].z, pa[0].w,
                           pa[1].x, pa[1].y, pa[1].z, pa[1].w};
#pragma unroll
            for (int j = 0; j < 8; ++j) {
                ah[j] = f2bf(va[j]);
                al[j] = f2bf(va[j] - __uint_as_float(((uint)ah[j]) << 16));
            }
#pragma unroll
            for (int c4 = 0; c4 < 4; ++c4) {
                float vb[4] = {pb[c4].x, pb[c4].y, pb[c4].z, pb[c4].w};
#pragma unroll
                for (int j = 0; j < 4; ++j) {
                    ushort g = f2bf(vb[j]);
                    bh[c4 * 4 + j] = g;
                    bl[c4 * 4 + j] = f2bf(vb[j] - __uint_as_float(((uint)g) << 16));
                }
            }
            const int aoff = arow * 72 + akc;
            *(uint4*)&As_hi[aoff] = pack8(ah);
            *(uint4*)&As_lo[aoff] = pack8(al);
            const int boff = brow * 72 + bkq;
            *(uint4*)&Bs_hi[boff]     = pack8(bh);
            *(uint4*)&Bs_hi[boff + 8] = pack8(bh + 8);
            *(uint4*)&Bs_lo[boff]     = pack8(bl);
            *(uint4*)&Bs_lo[boff + 8] = pack8(bl + 8);
        }
        __syncthreads();
        if (kb + 64 < FIN) {   // prefetch next panel during compute
#pragma unroll
            for (int c = 0; c < 2; ++c) pa[c] = *(const float4*)(xrow + kb + 64 + c * 4);
#pragma unroll
            for (int c = 0; c < 4; ++c) pb[c] = *(const float4*)(wrg + kb + 64 + c * 4);
        }
#pragma unroll
        for (int ch = 0; ch < 2; ++ch) {
            const int ko = ch * 32 + lq * 8;
            short8 ah = *(const short8*)&As_hi[(mbase + lm) * 72 + ko];
            short8 al = *(const short8*)&As_lo[(mbase + lm) * 72 + ko];
#pragma unroll
            for (int ti = 0; ti < 2; ++ti) {
                short8 bh = *(const short8*)&Bs_hi[(nbase + ti * 16 + lm) * 72 + ko];
                short8 bl = *(const short8*)&Bs_lo[(nbase + ti * 16 + lm) * 72 + ko];
                acc[ti] = __builtin_amdgcn_mfma_f32_16x16x32_bf16(ah, bh, acc[ti], 0, 0, 0);
                acc[ti] = __builtin_amdgcn_mfma_f32_16x16x32_bf16(al, bh, acc[ti], 0, 0, 0);
                acc[ti] = __builtin_amdgcn_mfma_f32_16x16x32_bf16(ah, bl, acc[ti], 0, 0, 0);
            }
        }
    }

    // epilogue: bias, clamp, per-token l1norm over 64 outs, store.
    const float b0 = eb[head * 64 + nbase + lm];
    const float b1 = eb[head * 64 + nbase + 16 + lm];
    float xe[2][4];
    float rs[4];
#pragma unroll
    for (int r = 0; r < 4; ++r) {
        float e0 = fmaxf(acc[0][r] + b0, 1e-6f);
        float e1 = fmaxf(acc[1][r] + b1, 1e-6f);
        xe[0][r] = e0; xe[1][r] = e1;
        float p = e0 + e1;
        p += __shfl_xor(p, 1, 64);
        p += __shfl_xor(p, 2, 64);
        p += __shfl_xor(p, 4, 64);
        p += __shfl_xor(p, 8, 64);
        rs[r] = p;
    }
    if (lm == 0) {
#pragma unroll
        for (int r = 0; r < 4; ++r)
            RS[(wv & 1) * 32 + mbase + lq * 4 + r] = rs[r];
    }
    __syncthreads();
    const size_t obase = ((size_t)((tok0 >> 10) * 12 + head) * 1024 + (tok0 & 1023));
#pragma unroll
    for (int r = 0; r < 4; ++r) {
        const int m = mbase + lq * 4 + r;
        const float inv = 1.f / fmaxf(RS[m] + RS[32 + m], 1e-20f);
        float* op = inp + (obase + m) * 64;
        op[nbase + lm]      = xe[0][r] * inv;
        op[nbase + 16 + lm] = xe[1][r] * inv;
    }
}

// ---------------------------------------------------------------------------
// K3 (MFMA, spill-free): NNMF updates, 16 tokens per wave, 384 blocks x 4 waves.
// W fragments live in block-shared LDS planes (hi/lo, [64][72] ushort) instead
// of 128 spilled VGPRs per wave; matvecs read B-frags via ds_read_b128.
// T is wave-private -> wave_barrier only.
// ---------------------------------------------------------------------------
__device__ __forceinline__ void mfma_matvec(const float srcC[4][4], float* T,
                                            int lm, int lq,
                                            const ushort* WH, const ushort* WL,
                                            floatx4 out[4]) {
    __builtin_amdgcn_wave_barrier();
#pragma unroll
    for (int nt = 0; nt < 4; ++nt)
#pragma unroll
        for (int r = 0; r < 4; ++r)
            T[(lq * 4 + r) * 68 + nt * 16 + lm] = srcC[nt][r];
    __builtin_amdgcn_wave_barrier();
    float4 a00 = *(const float4*)&T[lm * 68 + lq * 8];
    float4 a01 = *(const float4*)&T[lm * 68 + lq * 8 + 4];
    float4 a10 = *(const float4*)&T[lm * 68 + 32 + lq * 8];
    float4 a11 = *(const float4*)&T[lm * 68 + 32 + lq * 8 + 4];
    __builtin_amdgcn_wave_barrier();
    short8 A0h, A0l, A1h, A1l;
    split8v(a00, a01, A0h, A0l);
    split8v(a10, a11, A1h, A1l);
#pragma unroll
    for (int nt = 0; nt < 4; ++nt) {
        const int row = (nt * 16 + lm) * 72;
        short8 b0h = *(const short8*)&WH[row + lq * 8];
        short8 b0l = *(const short8*)&WL[row + lq * 8];
        short8 b1h = *(const short8*)&WH[row + 32 + lq * 8];
        short8 b1l = *(const short8*)&WL[row + 32 + lq * 8];
        floatx4 acc = (floatx4)0.f;
        acc = __builtin_amdgcn_mfma_f32_16x16x32_bf16(A0h, b0h, acc, 0, 0, 0);
        acc = __builtin_amdgcn_mfma_f32_16x16x32_bf16(A0l, b0h, acc, 0, 0, 0);
        acc = __builtin_amdgcn_mfma_f32_16x16x32_bf16(A0h, b0l, acc, 0, 0, 0);
        acc = __builtin_amdgcn_mfma_f32_16x16x32_bf16(A1h, b1h, acc, 0, 0, 0);
        acc = __builtin_amdgcn_mfma_f32_16x16x32_bf16(A1l, b1h, acc, 0, 0, 0);
        acc = __builtin_amdgcn_mfma_f32_16x16x32_bf16(A1h, b1l, acc, 0, 0, 0);
        out[nt] = acc;
    }
}

__global__ __launch_bounds__(256) void k_nnmf(const float* __restrict__ inp,
                                              const float* __restrict__ Wn,
                                              const float* __restrict__ WnT,
                                              const float* __restrict__ r1inv,
                                              float* __restrict__ hout,
                                              float* __restrict__ hriout,
                                              float* __restrict__ mp0) {
    // B-frag planes: Wt* from WnT (matvec1: t = h@W), Ww* from Wn (matvec2: u = q@W^T)
    __shared__ ushort WtH[64 * 72], WtL[64 * 72];
    __shared__ ushort WwH[64 * 72], WwL[64 * 72];
    __shared__ float Tb[4][16 * 68];
    const int tid = threadIdx.x, wv = tid >> 6, lane = tid & 63;
    const int lm = lane & 15, lq = lane >> 4;
    float* T = Tb[wv];
    const int rowbase = blockIdx.x * 64 + wv * 16;

    {   // stage W planes: thread -> row tid>>2, k-quarter (tid&3)*16
        const int row = tid >> 2, kq = (tid & 3) * 16;
        short8 h0, l0, h1, l1;
        split8v(*(const float4*)(WnT + row * 64 + kq), *(const float4*)(WnT + row * 64 + kq + 4), h0, l0);
        split8v(*(const float4*)(WnT + row * 64 + kq + 8), *(const float4*)(WnT + row * 64 + kq + 12), h1, l1);
        *(short8*)&WtH[row * 72 + kq] = h0; *(short8*)&WtH[row * 72 + kq + 8] = h1;
        *(short8*)&WtL[row * 72 + kq] = l0; *(short8*)&WtL[row * 72 + kq + 8] = l1;
        split8v(*(const float4*)(Wn + row * 64 + kq), *(const float4*)(Wn + row * 64 + kq + 4), h0, l0);
        split8v(*(const float4*)(Wn + row * 64 + kq + 8), *(const float4*)(Wn + row * 64 + kq + 12), h1, l1);
        *(short8*)&WwH[row * 72 + kq] = h0; *(short8*)&WwH[row * 72 + kq + 8] = h1;
        *(short8*)&WwL[row * 72 + kq] = l0; *(short8*)&WwL[row * 72 + kq + 8] = l1;
    }

    float inpC[4][4];
#pragma unroll
    for (int nt = 0; nt < 4; ++nt)
#pragma unroll
        for (int r = 0; r < 4; ++r)
            inpC[nt][r] = inp[(size_t)(rowbase + lq * 4 + r) * 64 + nt * 16 + lm];
    float r1c[4];
#pragma unroll
    for (int nt = 0; nt < 4; ++nt) r1c[nt] = r1inv[nt * 16 + lm];
    __syncthreads();   // W planes ready

    float hC[4][4], recC[4][4];
    {   // ---- iteration 1 (rec1 token-independent) ----
        float qC[4][4];
#pragma unroll
        for (int nt = 0; nt < 4; ++nt)
#pragma unroll
            for (int r = 0; r < 4; ++r) qC[nt][r] = inpC[nt][r] * r1c[nt];
        floatx4 u[4];
        mfma_matvec(qC, T, lm, lq, WwH, WwL, u);
#pragma unroll
        for (int nt = 0; nt < 4; ++nt)
#pragma unroll
            for (int r = 0; r < 4; ++r)
                hC[nt][r] = fmaxf(u[nt][r] * (1.f / 64.f), 1e-6f);
#pragma unroll
        for (int r = 0; r < 4; ++r) {
            float s = (hC[0][r] + hC[1][r]) + (hC[2][r] + hC[3][r]);
            s += __shfl_xor(s, 1, 64); s += __shfl_xor(s, 2, 64);
            s += __shfl_xor(s, 4, 64); s += __shfl_xor(s, 8, 64);
            const float inv = __builtin_amdgcn_rcpf(fmaxf(s, 1e-20f));
#pragma unroll
            for (int nt = 0; nt < 4; ++nt) hC[nt][r] *= inv;
        }
    }
#pragma unroll 1
    for (int it = 0; it < 2; ++it) {   // ---- iterations 2,3 (full) ----
        floatx4 t[4];
        mfma_matvec(hC, T, lm, lq, WtH, WtL, t);
        float tC[4][4], qC[4][4];
#pragma unroll
        for (int nt = 0; nt < 4; ++nt)
#pragma unroll
            for (int r = 0; r < 4; ++r) tC[nt][r] = fmaxf(t[nt][r], 1e-6f);
#pragma unroll
        for (int r = 0; r < 4; ++r) {
            float s = (tC[0][r] + tC[1][r]) + (tC[2][r] + tC[3][r]);
            s += __shfl_xor(s, 1, 64); s += __shfl_xor(s, 2, 64);
            s += __shfl_xor(s, 4, 64); s += __shfl_xor(s, 8, 64);
            s = fmaxf(s, 1e-20f);
            const float invS = __builtin_amdgcn_rcpf(s);
#pragma unroll
            for (int nt = 0; nt < 4; ++nt) {
                recC[nt][r] = tC[nt][r] * invS;
                qC[nt][r] = inpC[nt][r] * s * __builtin_amdgcn_rcpf(tC[nt][r]);
            }
        }
        floatx4 u[4];
        mfma_matvec(qC, T, lm, lq, WwH, WwL, u);
#pragma unroll
        for (int nt = 0; nt < 4; ++nt)
#pragma unroll
            for (int r = 0; r < 4; ++r)
                hC[nt][r] = fmaxf(hC[nt][r] * u[nt][r], 1e-6f);
#pragma unroll
        for (int r = 0; r < 4; ++r) {
            float s = (hC[0][r] + hC[1][r]) + (hC[2][r] + hC[3][r]);
            s += __shfl_xor(s, 1, 64); s += __shfl_xor(s, 2, 64);
            s += __shfl_xor(s, 4, 64); s += __shfl_xor(s, 8, 64);
            const float inv = __builtin_amdgcn_rcpf(fmaxf(s, 1e-20f));
#pragma unroll
            for (int nt = 0; nt < 4; ++nt) hC[nt][r] *= inv;
        }
    }
#pragma unroll
    for (int r = 0; r < 4; ++r) {
        float s = (hC[0][r] + hC[1][r]) + (hC[2][r] + hC[3][r]);
        s += __shfl_xor(s, 1, 64); s += __shfl_xor(s, 2, 64);
        s += __shfl_xor(s, 4, 64); s += __shfl_xor(s, 8, 64);
        const float inv = __builtin_amdgcn_rcpf(fmaxf(s, 1e-20f));
#pragma unroll
        for (int nt = 0; nt < 4; ++nt) hC[nt][r] *= inv;
    }
#pragma unroll
    for (int nt = 0; nt < 4; ++nt)
#pragma unroll
        for (int r = 0; r < 4; ++r) {
            const size_t o = (size_t)(rowbase + lq * 4 + r) * 64 + nt * 16 + lm;
            hout[o] = hC[nt][r];
            hriout[o] = recC[nt][r] * inpC[nt][r];
        }
    float hs[4];
#pragma unroll
    for (int nt = 0; nt < 4; ++nt) {
        float s = (hC[nt][0] + hC[nt][1]) + (hC[nt][2] + hC[nt][3]);
        s += __shfl_xor(s, 16, 64);
        s += __shfl_xor(s, 32, 64);
        hs[nt] = s;
    }
    float mvv = lq == 0 ? hs[0] : lq == 1 ? hs[1] : lq == 2 ? hs[2] : hs[3];
    atomicAdd(&mp0[(size_t)blockIdx.x * 64 + lq * 16 + lm], mvv);
}

// ---------------------------------------------------------------------------
// K4: one alpha iteration per launch, 384 blocks = (bh) x (64-o chunk).
// ---------------------------------------------------------------------------
__global__ __launch_bounds__(256) void k_alpha_step(const float* __restrict__ hin,
                                                    const float* __restrict__ hri,
                                                    const float* __restrict__ Wn,
                                                    const float* __restrict__ mp_in,
                                                    float* __restrict__ mp_out,
                                                    float* __restrict__ c,
                                                    float* __restrict__ M,
                                                    int it) {
    __shared__ float mred[4][64];
    __shared__ float mv[64];
    __shared__ float vv[64];
    __shared__ float cl[64];
    const int tid = threadIdx.x;
    const int bh = blockIdx.x >> 4;
    const int chunk = blockIdx.x & 15;
    const size_t rowbase = (size_t)bh * 1024 + chunk * 64;

    {
        int f = tid & 63, p = tid >> 6;
        float s = 0.f;
#pragma unroll
        for (int pp = 0; pp < 4; ++pp)
            s += mp_in[((size_t)bh * 16 + p * 4 + pp) * 64 + f];
        mred[p][f] = s;
    }
    __syncthreads();
    if (tid < 64)
        mv[tid] = (mred[0][tid] + mred[1][tid]) + (mred[2][tid] + mred[3][tid]);
    __syncthreads();
    {
        int d = tid & 63, qq = tid >> 6;
        float r = 0.f;
#pragma unroll
        for (int ff = 0; ff < 16; ++ff)
            r = fmaf(mv[qq * 16 + ff], Wn[(size_t)(qq * 16 + ff) * 64 + d], r);
        mred[qq][d] = r;
    }
    __syncthreads();
    if (tid < 64)
        vv[tid] = 1.f / (((mred[0][tid] + mred[1][tid]) + (mred[2][tid] + mred[3][tid])) + 1e-20f);
    __syncthreads();
    {
        int o = tid >> 2, dq = tid & 3;
        const float* rp = hri + (rowbase + o) * 64 + dq * 16;
        float dot = 0.f;
#pragma unroll
        for (int t4 = 0; t4 < 16; t4 += 4) {
            float4 r4 = *(const float4*)(rp + t4);
            dot = fmaf(r4.x, vv[dq * 16 + t4 + 0], dot);
            dot = fmaf(r4.y, vv[dq * 16 + t4 + 1], dot);
            dot = fmaf(r4.z, vv[dq * 16 + t4 + 2], dot);
            dot = fmaf(r4.w, vv[dq * 16 + t4 + 3], dot);
        }
        dot += __shfl_xor(dot, 1, 64);
        dot += __shfl_xor(dot, 2, 64);
        float cn = dot;
        if (it >= 2) cn *= c[rowbase + o];
        if (dq == 0) { c[rowbase + o] = cn; cl[o] = cn; }
    }
    __syncthreads();
    {
        const int f4 = (tid & 15) * 4, ogr = tid >> 4;
        float4 a = make_float4(0.f, 0.f, 0.f, 0.f);
#pragma unroll
        for (int oi = 0; oi < 4; ++oi) {
            int o = ogr * 4 + oi;
            float4 h4 = *(const float4*)(hin + (rowbase + o) * 64 + f4);
            float cv = cl[o];
            a.x = fmaf(h4.x, cv, a.x); a.y = fmaf(h4.y, cv, a.y);
            a.z = fmaf(h4.z, cv, a.z); a.w = fmaf(h4.w, cv, a.w);
        }
        a.x += __shfl_xor(a.x, 16, 64); a.y += __shfl_xor(a.y, 16, 64);
        a.z += __shfl_xor(a.z, 16, 64); a.w += __shfl_xor(a.w, 16, 64);
        a.x += __shfl_xor(a.x, 32, 64); a.y += __shfl_xor(a.y, 32, 64);
        a.z += __shfl_xor(a.z, 32, 64); a.w += __shfl_xor(a.w, 32, 64);
        const int w = tid >> 6;
        if ((tid & 63) < 16) *(float4*)&mred[w][(tid & 15) * 4] = a;
    }
    __syncthreads();
    if (tid < 64) {
        float s = (mred[0][tid] + mred[1][tid]) + (mred[2][tid] + mred[3][tid]);
        if (it == 3) atomicAdd(&M[(size_t)bh * 64 + tid], s);
        else mp_out[((size_t)bh * 16 + chunk) * 64 + tid] = s;
    }
}

// ---------------------------------------------------------------------------
// K5: out-projection + broadcast, 384 blocks = (b) x (12 out-seg) x (16 rowgrp).
// ---------------------------------------------------------------------------
__global__ __launch_bounds__(256) void k_projbcast(const float* __restrict__ M,
                                                   const float* __restrict__ ow,
                                                   const float* __restrict__ ob,
                                                   float* __restrict__ out) {
    __shared__ float Ml[768];
    __shared__ float ps[4][64];
    __shared__ float yseg[64];
    const int tid = threadIdx.x;
    const int b = blockIdx.x / 192;
    const int rem = blockIdx.x - b * 192;
    const int jt = rem >> 4, rg = rem & 15;
    for (int i = tid; i < 768; i += 256) Ml[i] = M[b * 768 + i];
    __syncthreads();
    const int jj = tid & 63, part = tid >> 6;
    const int j = jt * 64 + jj;
    const float* row = ow + (size_t)j * 768 + part * 192;
    float acc = 0.f;
    for (int t = 0; t < 192; t += 4) {
        float4 w4 = *(const float4*)(row + t);
        acc = fmaf(w4.x, Ml[part * 192 + t + 0], acc);
        acc = fmaf(w4.y, Ml[part * 192 + t + 1], acc);
        acc = fmaf(w4.z, Ml[part * 192 + t + 2], acc);
        acc = fmaf(w4.w, Ml[part * 192 + t + 3], acc);
    }
    ps[part][jj] = acc;
    __syncthreads();
    if (tid < 64)
        yseg[tid] = ps[0][tid] + ps[1][tid] + ps[2][tid] + ps[3][tid] + ob[jt * 64 + tid];
    __syncthreads();
    const int r0 = tid >> 2, c4 = (tid & 3) * 16;
    float4 v4[4];
#pragma unroll
    for (int q = 0; q < 4; ++q) v4[q] = *(const float4*)&yseg[c4 + q * 4];
    float* dst = out + ((size_t)(b * 1024 + rg * 64 + r0)) * 768 + jt * 64 + c4;
#pragma unroll
    for (int q = 0; q < 4; ++q) *(float4*)(dst + q * 4) = v4[q];
}

extern "C" void kernel_launch(void* const* d_in, const int* in_sizes, int n_in,
                              void* d_out, int out_size, void* d_ws, size_t ws_size,
                              hipStream_t stream) {
    const float* xs = (const float*)d_in[0];  // [2,1024,768]
    const float* ew = (const float*)d_in[1];  // [768,768]
    const float* eb = (const float*)d_in[2];  // [768]
    const float* nw = (const float*)d_in[3];  // [64,64]
    const float* ow = (const float*)d_in[4];  // [768,768]
    const float* ob = (const float*)d_in[5];  // [768]
    float* out = (float*)d_out;               // [2,1024,768]

    float* ws    = (float*)d_ws;
    float* inp   = ws;                 // 1572864
    float* h     = ws + 1572864;       // 1572864
    float* hri   = ws + 3145728;       // 1572864
    float* Wn    = ws + 4718592;       // 4096
    float* WnT   = ws + 4722688;       // 4096
    float* r1inv = ws + 4726784;       // 256
    float* mp0   = ws + 4727040;       // 24576 (atomic target, zeroed in-kernel)
    float* M     = ws + 4751616;       // 1536  (atomic target, zeroed in-kernel)
    float* mp1   = ws + 4753152;       // 24576
    float* mp2   = ws + 4777728;       // 24576
    float* c     = ws + 4802304;       // 24576

    k_embed_prep<<<795, 256, 0, stream>>>(xs, ew, eb, nw, Wn, WnT, r1inv, mp0, inp);
    k_nnmf<<<384, 256, 0, stream>>>(inp, Wn, WnT, r1inv, h, hri, mp0);
    k_alpha_step<<<384, 256, 0, stream>>>(h, hri, Wn, mp0, mp1, c, M, 1);
    k_alpha_step<<<384, 256, 0, stream>>>(h, hri, Wn, mp1, mp2, c, M, 2);
    k_alpha_step<<<384, 256, 0, stream>>>(h, hri, Wn, mp2, mp1, c, M, 3);
    k_projbcast<<<384, 256, 0, stream>>>(M, ow, ob, out);
}